// Round 1
// baseline (151.998 us; speedup 1.0000x reference)
//
#include <hip/hip_runtime.h>
#include <hip/hip_bf16.h>

#define NN 8192
#define DD 128

typedef __attribute__((ext_vector_type(4))) float f32x4;
typedef __attribute__((ext_vector_type(8))) short bf16x8;

__device__ __forceinline__ short f2bf(float f) {
  __hip_bfloat16 h = __float2bfloat16(f);
  return __builtin_bit_cast(short, h);
}

// ---------------------------------------------------------------------------
// Kernel 1: yT[n][k] = sum_d x[k][d] * W[d][n]   (bf16, transposed)
// y = x @ W precomputed so main kernel does out = (A @ y) / degree.
// Transposed so the MFMA B-fragment (8 contiguous k per lane) is one 16B load.
// grid 256 x 256 threads; block handles 32 k-rows, wave-half handles 16 cols.
// ---------------------------------------------------------------------------
__global__ __launch_bounds__(256) void xw_kernel(
    const float* __restrict__ x, const float* __restrict__ W,
    short* __restrict__ yT)
{
  __shared__ float xs[32][129];   // +1 pad: bank = (kl + d) % 32, conflict-free
  const int t  = threadIdx.x;
  const int k0 = blockIdx.x * 32;

  #pragma unroll
  for (int i = 0; i < 4; ++i) {
    int idx = i * 256 + t;        // float4 index, 1024 total
    int row = idx >> 5;
    int c4  = (idx & 31) * 4;
    f32x4 v = *(const f32x4*)(x + (size_t)(k0 + row) * DD + c4);
    xs[row][c4 + 0] = v[0]; xs[row][c4 + 1] = v[1];
    xs[row][c4 + 2] = v[2]; xs[row][c4 + 3] = v[3];
  }
  __syncthreads();

  const int kl = t & 31;          // k row within tile
  const int g  = t >> 5;          // 0..7 -> 16-column group
  float acc[16];
  #pragma unroll
  for (int j = 0; j < 16; ++j) acc[j] = 0.f;

  for (int d = 0; d < 128; ++d) {
    float xv = xs[kl][d];         // same addr for lane l and l+32 -> broadcast
    const float* wr = W + d * DD + g * 16;
    f32x4 w0 = *(const f32x4*)(wr);
    f32x4 w1 = *(const f32x4*)(wr + 4);
    f32x4 w2 = *(const f32x4*)(wr + 8);
    f32x4 w3 = *(const f32x4*)(wr + 12);
    #pragma unroll
    for (int j = 0; j < 4; ++j) {
      acc[j]      += xv * w0[j];
      acc[4 + j]  += xv * w1[j];
      acc[8 + j]  += xv * w2[j];
      acc[12 + j] += xv * w3[j];
    }
  }
  #pragma unroll
  for (int j = 0; j < 16; ++j) {
    int n = g * 16 + j;
    yT[(size_t)n * NN + k0 + kl] = f2bf(acc[j]);
  }
}

// ---------------------------------------------------------------------------
// Kernel 2: out[m][n] = (sum_k A[m][k] * y[k][n]) / degree[m]
// 256 blocks x 512 threads (8 waves). Block owns 32 rows; wave w owns
// K in [w*1024, (w+1)*1024). MFMA 16x16x32 bf16, fp32 accumulate.
// Degree (row sums of A, fp32) fused into the same single pass over A.
// ---------------------------------------------------------------------------
__global__ __launch_bounds__(512, 2) void gcn_main(
    const float* __restrict__ A, const short* __restrict__ yT,
    float* __restrict__ out)
{
  const int tid   = threadIdx.x;
  const int l     = tid & 63;
  const int w     = tid >> 6;            // wave 0..7
  const int mbase = blockIdx.x * 32;
  const int l15   = l & 15;
  const int kl    = (l >> 4) * 8;        // k offset of this lane's 8 elements

  const float* arow0 = A + (size_t)(mbase + l15) * NN;
  const float* arow1 = arow0 + (size_t)16 * NN;

  f32x4 acc[2][8];
  #pragma unroll
  for (int f = 0; f < 2; ++f)
    #pragma unroll
    for (int n = 0; n < 8; ++n) acc[f][n] = (f32x4)0.f;
  float deg0 = 0.f, deg1 = 0.f;

  const int kbase = w * 1024;

  #pragma unroll 2
  for (int s = 0; s < 32; ++s) {
    const int k0 = kbase + s * 32 + kl;

    // A: 8 contiguous fp32 per lane per row-frag (non-temporal: streamed once)
    f32x4 a0lo = __builtin_nontemporal_load((const f32x4*)(arow0 + k0));
    f32x4 a0hi = __builtin_nontemporal_load((const f32x4*)(arow0 + k0 + 4));
    f32x4 a1lo = __builtin_nontemporal_load((const f32x4*)(arow1 + k0));
    f32x4 a1hi = __builtin_nontemporal_load((const f32x4*)(arow1 + k0 + 4));

    // B: 8 fragments of yT (L2/L3-resident, 2 MB total)
    bf16x8 b[8];
    #pragma unroll
    for (int n = 0; n < 8; ++n)
      b[n] = *(const bf16x8*)(yT + (size_t)(n * 16 + l15) * NN + k0);

    // fused degree partials (fp32, before bf16 rounding)
    deg0 += (a0lo[0] + a0lo[1]) + (a0lo[2] + a0lo[3])
          + (a0hi[0] + a0hi[1]) + (a0hi[2] + a0hi[3]);
    deg1 += (a1lo[0] + a1lo[1]) + (a1lo[2] + a1lo[3])
          + (a1hi[0] + a1hi[1]) + (a1hi[2] + a1hi[3]);

    bf16x8 a0, a1;
    #pragma unroll
    for (int j = 0; j < 4; ++j) {
      a0[j]     = f2bf(a0lo[j]);
      a0[4 + j] = f2bf(a0hi[j]);
      a1[j]     = f2bf(a1lo[j]);
      a1[4 + j] = f2bf(a1hi[j]);
    }

    #pragma unroll
    for (int n = 0; n < 8; ++n) {
      acc[0][n] = __builtin_amdgcn_mfma_f32_16x16x32_bf16(a0, b[n], acc[0][n], 0, 0, 0);
      acc[1][n] = __builtin_amdgcn_mfma_f32_16x16x32_bf16(a1, b[n], acc[1][n], 0, 0, 0);
    }
  }

  // ---- degree reduce: lane groups (xor 16, 32) then across waves in LDS ----
  __shared__ float degpart[8][32];
  __shared__ float degree[32];
  __shared__ float red[8][16][17];

  deg0 += __shfl_xor(deg0, 16); deg0 += __shfl_xor(deg0, 32);
  deg1 += __shfl_xor(deg1, 16); deg1 += __shfl_xor(deg1, 32);
  if (l < 16) { degpart[w][l] = deg0; degpart[w][16 + l] = deg1; }
  __syncthreads();
  if (tid < 32) {
    float s = 0.f;
    #pragma unroll
    for (int ww = 0; ww < 8; ++ww) s += degpart[ww][tid];
    degree[tid] = s;
  }
  __syncthreads();

  // ---- accumulator cross-wave reduce, 16 chunks of one 16x16 fragment ----
  for (int c = 0; c < 16; ++c) {
    const int f = c >> 3, n = c & 7;
    #pragma unroll
    for (int i = 0; i < 4; ++i)
      red[w][(l >> 4) * 4 + i][l15] = acc[f][n][i];
    __syncthreads();
    if (tid < 256) {
      int row = tid >> 4, col = tid & 15;
      float s = 0.f;
      #pragma unroll
      for (int ww = 0; ww < 8; ++ww) s += red[ww][row][col];
      int gr = mbase + f * 16 + row;
      out[(size_t)gr * DD + n * 16 + col] = s / degree[f * 16 + row];
    }
    __syncthreads();
  }
}

extern "C" void kernel_launch(void* const* d_in, const int* in_sizes, int n_in,
                              void* d_out, int out_size, void* d_ws, size_t ws_size,
                              hipStream_t stream) {
  const float* x = (const float*)d_in[0];   // [8192,128] fp32
  const float* A = (const float*)d_in[1];   // [8192,8192] fp32
  const float* W = (const float*)d_in[2];   // [128,128] fp32
  float* out = (float*)d_out;               // [8192,128] fp32
  short* yT  = (short*)d_ws;                // bf16 [128][8192] = 2 MB scratch

  xw_kernel<<<256, 256, 0, stream>>>(x, W, yT);
  gcn_main<<<256, 512, 0, stream>>>(A, yT, out);
}